// Round 2
// baseline (368.352 us; speedup 1.0000x reference)
//
#include <hip/hip_runtime.h>
#include <math.h>

#define T_DIM 64
#define U_DIM 142
#define I_DIM 4500
#define B_DIM 16384
#define K_TOP 10
#define U_PAD 144   // compact row stride (9 full 64B lines)

// ---------------- pass 1: slotmap = -1 (ws poisoned 0xAA each call) ---------
__global__ __launch_bounds__(256) void k_clear(int* __restrict__ slotmap) {
    const int idx = blockIdx.x * 256 + threadIdx.x;   // grid covers T*I exactly
    slotmap[idx] = -1;
}

// ---------------- pass 2: owner per distinct (t,i) --------------------------
__global__ __launch_bounds__(256) void k_assign(const int* __restrict__ iid,
                                                const int* __restrict__ tid,
                                                int* __restrict__ slotmap) {
    const int b  = blockIdx.x * 256 + threadIdx.x;    // grid covers B exactly
    const int ti = tid[b] * I_DIM + iid[b];
    atomicCAS(&slotmap[ti], -1, b);   // first b wins; losers look it up later
}

// ---------------- pass 3: stream qos, scatter needed columns ----------------
// block = (u-chunk of 16, t). Each compact 64B line (16 u's) is written only
// by this block -> no cross-XCD line sharing, minimal write amplification.
// Reads: full 18KB rows, perfectly sequential. slotmap row (18KB) is
// L1-resident across the block's 16 rows.
__global__ __launch_bounds__(256) void k_extract(const float* __restrict__ qos,
                                                 const int* __restrict__ slotmap,
                                                 float* __restrict__ compact) {
    const int lane = threadIdx.x & 63;
    const int w    = threadIdx.x >> 6;          // wave id 0..3
    const int t    = blockIdx.y;
    const int u0   = blockIdx.x * 16;
    const int4* smap4 = (const int4*)(slotmap + (size_t)t * I_DIM);
#pragma unroll
    for (int r = 0; r < 4; ++r) {
        const int u = u0 + w + r * 4;           // wave-uniform
        if (u >= U_DIM) break;
        const float4* row4 = (const float4*)(qos + ((size_t)t * U_DIM + u) * I_DIM);
        for (int it = 0; it < 18; ++it) {       // 1125 float4 per row
            const int idx4 = it * 64 + lane;
            if (idx4 < 1125) {
                const float4 qv = row4[idx4];
                const int4   ov = smap4[idx4];  // mostly -1 (94%)
                if (ov.x >= 0) compact[(size_t)ov.x * U_PAD + u] = qv.x;
                if (ov.y >= 0) compact[(size_t)ov.y * U_PAD + u] = qv.y;
                if (ov.z >= 0) compact[(size_t)ov.z * U_PAD + u] = qv.z;
                if (ov.w >= 0) compact[(size_t)ov.w * U_PAD + u] = qv.w;
            }
        }
    }
}

// ---------------- pass 4: wave-per-b top-k (round-0 proven) -----------------
__global__ __launch_bounds__(256) void k_final(
    const float* __restrict__ compact,
    const float* __restrict__ user_avg,  // [T,U]
    const float* __restrict__ user_sim,  // [U,U]
    const int*   __restrict__ uid,
    const int*   __restrict__ iid,
    const int*   __restrict__ tid,
    const int*   __restrict__ slotmap,
    float*       __restrict__ out)
{
    const int lane = threadIdx.x & 63;
    const int wid  = threadIdx.x >> 6;
    const int b    = blockIdx.x * 4 + wid;      // grid covers B exactly

    const int u = uid[b];
    const int i = iid[b];
    const int t = tid[b];
    const int o = slotmap[t * I_DIM + i];       // guaranteed >= 0 after assign

    const float* crow = compact + (size_t)o * U_PAD;   // contiguous 568 B
    const float* srow = user_sim + (size_t)u * U_DIM;
    const float* arow = user_avg + (size_t)t * U_DIM;

    float val[3], con[3];
#pragma unroll
    for (int j = 0; j < 3; ++j) {
        const int v = lane + j * 64;
        float sv = -INFINITY, cv = 0.0f;
        if (v < U_DIM) {
            const float rv = crow[v];
            const float av = arow[v];
            const float s  = srow[v];
            sv = (rv > 0.0f) ? s : 0.0f;
            cv = sv * (rv - av);
        }
        val[j] = sv; con[j] = cv;
    }

    float ssum = 0.0f, wsum = 0.0f;
#pragma unroll
    for (int k = 0; k < K_TOP; ++k) {
        float mv = val[0]; float mc = con[0]; int mk = lane;
        if (val[1] > mv) { mv = val[1]; mc = con[1]; mk = lane + 64; }
        if (val[2] > mv) { mv = val[2]; mc = con[2]; mk = lane + 128; }
#pragma unroll
        for (int off = 32; off > 0; off >>= 1) {
            const float ov = __shfl_xor(mv, off, 64);
            const float oc = __shfl_xor(mc, off, 64);
            const int   ok = __shfl_xor(mk, off, 64);
            if (ov > mv || (ov == mv && ok < mk)) { mv = ov; mc = oc; mk = ok; }
        }
        ssum += mv; wsum += mc;
        if ((mk & 63) == lane) {
            const int slot = mk >> 6;
            if (slot == 0)      val[0] = -INFINITY;
            else if (slot == 1) val[1] = -INFINITY;
            else                val[2] = -INFINITY;
        }
    }

    if (lane == 0) out[b] = arow[u] + wsum / (ssum + 1e-8f);
}

// ---------------- fallback (round-0 random-gather kernel) -------------------
__global__ __launch_bounds__(256) void ucf_fallback(
    const float* __restrict__ qos, const float* __restrict__ user_avg,
    const float* __restrict__ user_sim, const int* __restrict__ uid,
    const int* __restrict__ iid, const int* __restrict__ tid,
    float* __restrict__ out)
{
    const int lane = threadIdx.x & 63;
    const int wid  = threadIdx.x >> 6;
    const int b    = blockIdx.x * 4 + wid;
    const int u = uid[b], i = iid[b], t = tid[b];
    const float* qcol = qos + ((size_t)t * U_DIM) * (size_t)I_DIM + i;
    const float* srow = user_sim + (size_t)u * U_DIM;
    const float* arow = user_avg + (size_t)t * U_DIM;
    float val[3], con[3];
#pragma unroll
    for (int j = 0; j < 3; ++j) {
        const int v = lane + j * 64;
        float sv = -INFINITY, cv = 0.0f;
        if (v < U_DIM) {
            const float rv = qcol[(size_t)v * I_DIM];
            sv = (rv > 0.0f) ? srow[v] : 0.0f;
            cv = sv * (rv - arow[v]);
        }
        val[j] = sv; con[j] = cv;
    }
    float ssum = 0.0f, wsum = 0.0f;
#pragma unroll
    for (int k = 0; k < K_TOP; ++k) {
        float mv = val[0]; float mc = con[0]; int mk = lane;
        if (val[1] > mv) { mv = val[1]; mc = con[1]; mk = lane + 64; }
        if (val[2] > mv) { mv = val[2]; mc = con[2]; mk = lane + 128; }
#pragma unroll
        for (int off = 32; off > 0; off >>= 1) {
            const float ov = __shfl_xor(mv, off, 64);
            const float oc = __shfl_xor(mc, off, 64);
            const int   ok = __shfl_xor(mk, off, 64);
            if (ov > mv || (ov == mv && ok < mk)) { mv = ov; mc = oc; mk = ok; }
        }
        ssum += mv; wsum += mc;
        if ((mk & 63) == lane) {
            const int slot = mk >> 6;
            if (slot == 0)      val[0] = -INFINITY;
            else if (slot == 1) val[1] = -INFINITY;
            else                val[2] = -INFINITY;
        }
    }
    if (lane == 0) out[b] = arow[u] + wsum / (ssum + 1e-8f);
}

extern "C" void kernel_launch(void* const* d_in, const int* in_sizes, int n_in,
                              void* d_out, int out_size, void* d_ws, size_t ws_size,
                              hipStream_t stream) {
    const float* qos  = (const float*)d_in[0];
    const float* uavg = (const float*)d_in[1];
    const float* usim = (const float*)d_in[2];
    const int*   uid  = (const int*)d_in[3];
    const int*   iid  = (const int*)d_in[4];
    const int*   tid  = (const int*)d_in[5];
    float* out = (float*)d_out;

    // ws layout: slotmap [T*I] ints | compact [B][U_PAD] floats
    const size_t smap_bytes = (size_t)T_DIM * I_DIM * sizeof(int);           // 1.152 MB
    const size_t off_compact = (smap_bytes + 255) & ~(size_t)255;
    const size_t need = off_compact + (size_t)B_DIM * U_PAD * sizeof(float); // ~10.6 MB

    if (ws_size >= need) {
        int*   slotmap = (int*)d_ws;
        float* compact = (float*)((char*)d_ws + off_compact);

        k_clear  <<<(T_DIM * I_DIM) / 256, 256, 0, stream>>>(slotmap);
        k_assign <<<B_DIM / 256,           256, 0, stream>>>(iid, tid, slotmap);
        dim3 eg((U_DIM + 15) / 16, T_DIM);           // (9, 64)
        k_extract<<<eg,                    256, 0, stream>>>(qos, slotmap, compact);
        k_final  <<<B_DIM / 4,             256, 0, stream>>>(compact, uavg, usim,
                                                             uid, iid, tid, slotmap, out);
    } else {
        ucf_fallback<<<B_DIM / 4, 256, 0, stream>>>(qos, uavg, usim, uid, iid, tid, out);
    }
}

// Round 4
// 337.387 us; speedup vs baseline: 1.0918x; 1.0918x over previous
//
#include <hip/hip_runtime.h>
#include <math.h>

#define T_DIM 64
#define U_DIM 142
#define I_DIM 4500
#define I4_DIM 1125   // I_DIM/4
#define B_DIM 16384
#define K_TOP 10
#define U_PAD 144     // compact row stride (9 full 64B lines)

// ---------------- pass 1: slotmap = -1 (ws poisoned 0xAA each call) ---------
__global__ __launch_bounds__(256) void k_clear(int* __restrict__ slotmap) {
    const int idx = blockIdx.x * 256 + threadIdx.x;   // grid covers T*I exactly
    slotmap[idx] = -1;
}

// ---------------- pass 2: owner slot per distinct (t,i) ---------------------
__global__ __launch_bounds__(256) void k_assign(const int* __restrict__ iid,
                                                const int* __restrict__ tid,
                                                int* __restrict__ slotmap) {
    const int b  = blockIdx.x * 256 + threadIdx.x;    // grid covers B exactly
    const int ti = tid[b] * I_DIM + iid[b];
    atomicCAS(&slotmap[ti], -1, b);   // first b wins; losers look it up later
}

// ---------------- pass 3: sparse extract ------------------------------------
// Block = (i4-chunk of 256, u-chunk of 16, t). Thread owns one i4 (4 items).
// Reads slotmap int4 once; retires ONLY if all four slots are empty
// (sign bit survives AND iff all four are -1 — R2 used OR, which skipped any
// int4 containing a single -1 and left poison in compact: the absmax-1.75 bug).
// qos float4 loads below only fetch HIT lines (~60% of lines, ~98 MB total)
// instead of streaming all 163 MB.
// Write-line ownership: compact line (slot, u0..u0+15) = 64B, written only by
// this block (U_PAD%16==0 keeps u-chunks line-aligned) -> no cross-XCD
// partial-line sharing.
__global__ __launch_bounds__(256) void k_extract(const float* __restrict__ qos,
                                                 const int* __restrict__ slotmap,
                                                 float* __restrict__ compact) {
    const int i4 = blockIdx.x * 256 + threadIdx.x;
    if (i4 >= I4_DIM) return;
    const int t  = blockIdx.z;
    const int u0 = blockIdx.y * 16;
    const int un = (u0 + 16 <= U_DIM) ? 16 : (U_DIM - u0);

    const int4 ov = ((const int4*)(slotmap + (size_t)t * I_DIM))[i4];
    if ((ov.x & ov.y & ov.z & ov.w) < 0) return;   // ALL -1: nothing needed

    const float4* qcol4 = (const float4*)qos + ((size_t)t * U_DIM + u0) * I4_DIM + i4;
#pragma unroll 4
    for (int j = 0; j < un; ++j) {
        const float4 q = qcol4[(size_t)j * I4_DIM];   // only hit lines fetched
        const int u = u0 + j;
        if (ov.x >= 0) compact[(size_t)ov.x * U_PAD + u] = q.x;
        if (ov.y >= 0) compact[(size_t)ov.y * U_PAD + u] = q.y;
        if (ov.z >= 0) compact[(size_t)ov.z * U_PAD + u] = q.z;
        if (ov.w >= 0) compact[(size_t)ov.w * U_PAD + u] = q.w;
    }
}

// ---------------- pass 4: wave-per-b top-k (proven, absmax 0) ---------------
__global__ __launch_bounds__(256) void k_final(
    const float* __restrict__ compact,
    const float* __restrict__ user_avg,  // [T,U]
    const float* __restrict__ user_sim,  // [U,U]
    const int*   __restrict__ uid,
    const int*   __restrict__ iid,
    const int*   __restrict__ tid,
    const int*   __restrict__ slotmap,
    float*       __restrict__ out)
{
    const int lane = threadIdx.x & 63;
    const int wid  = threadIdx.x >> 6;
    const int b    = blockIdx.x * 4 + wid;      // grid covers B exactly

    const int u = uid[b];
    const int i = iid[b];
    const int t = tid[b];
    const int o = slotmap[t * I_DIM + i];       // >= 0 after assign

    const float* crow = compact + (size_t)o * U_PAD;   // contiguous 568 B
    const float* srow = user_sim + (size_t)u * U_DIM;
    const float* arow = user_avg + (size_t)t * U_DIM;

    float val[3], con[3];
#pragma unroll
    for (int j = 0; j < 3; ++j) {
        const int v = lane + j * 64;
        float sv = -INFINITY, cv = 0.0f;
        if (v < U_DIM) {
            const float rv = crow[v];
            const float av = arow[v];
            const float s  = srow[v];
            sv = (rv > 0.0f) ? s : 0.0f;
            cv = sv * (rv - av);
        }
        val[j] = sv; con[j] = cv;
    }

    float ssum = 0.0f, wsum = 0.0f;
#pragma unroll
    for (int k = 0; k < K_TOP; ++k) {
        float mv = val[0]; float mc = con[0]; int mk = lane;
        if (val[1] > mv) { mv = val[1]; mc = con[1]; mk = lane + 64; }
        if (val[2] > mv) { mv = val[2]; mc = con[2]; mk = lane + 128; }
#pragma unroll
        for (int off = 32; off > 0; off >>= 1) {
            const float ov = __shfl_xor(mv, off, 64);
            const float oc = __shfl_xor(mc, off, 64);
            const int   ok = __shfl_xor(mk, off, 64);
            if (ov > mv || (ov == mv && ok < mk)) { mv = ov; mc = oc; mk = ok; }
        }
        ssum += mv; wsum += mc;
        if ((mk & 63) == lane) {
            const int slot = mk >> 6;
            if (slot == 0)      val[0] = -INFINITY;
            else if (slot == 1) val[1] = -INFINITY;
            else                val[2] = -INFINITY;
        }
    }

    if (lane == 0) out[b] = arow[u] + wsum / (ssum + 1e-8f);
}

// ---------------- fallback (round-0 random-gather kernel) -------------------
__global__ __launch_bounds__(256) void ucf_fallback(
    const float* __restrict__ qos, const float* __restrict__ user_avg,
    const float* __restrict__ user_sim, const int* __restrict__ uid,
    const int* __restrict__ iid, const int* __restrict__ tid,
    float* __restrict__ out)
{
    const int lane = threadIdx.x & 63;
    const int wid  = threadIdx.x >> 6;
    const int b    = blockIdx.x * 4 + wid;
    const int u = uid[b], i = iid[b], t = tid[b];
    const float* qcol = qos + ((size_t)t * U_DIM) * (size_t)I_DIM + i;
    const float* srow = user_sim + (size_t)u * U_DIM;
    const float* arow = user_avg + (size_t)t * U_DIM;
    float val[3], con[3];
#pragma unroll
    for (int j = 0; j < 3; ++j) {
        const int v = lane + j * 64;
        float sv = -INFINITY, cv = 0.0f;
        if (v < U_DIM) {
            const float rv = qcol[(size_t)v * I_DIM];
            sv = (rv > 0.0f) ? srow[v] : 0.0f;
            cv = sv * (rv - arow[v]);
        }
        val[j] = sv; con[j] = cv;
    }
    float ssum = 0.0f, wsum = 0.0f;
#pragma unroll
    for (int k = 0; k < K_TOP; ++k) {
        float mv = val[0]; float mc = con[0]; int mk = lane;
        if (val[1] > mv) { mv = val[1]; mc = con[1]; mk = lane + 64; }
        if (val[2] > mv) { mv = val[2]; mc = con[2]; mk = lane + 128; }
#pragma unroll
        for (int off = 32; off > 0; off >>= 1) {
            const float ov = __shfl_xor(mv, off, 64);
            const float oc = __shfl_xor(mc, off, 64);
            const int   ok = __shfl_xor(mk, off, 64);
            if (ov > mv || (ov == mv && ok < mk)) { mv = ov; mc = oc; mk = ok; }
        }
        ssum += mv; wsum += mc;
        if ((mk & 63) == lane) {
            const int slot = mk >> 6;
            if (slot == 0)      val[0] = -INFINITY;
            else if (slot == 1) val[1] = -INFINITY;
            else                val[2] = -INFINITY;
        }
    }
    if (lane == 0) out[b] = arow[u] + wsum / (ssum + 1e-8f);
}

extern "C" void kernel_launch(void* const* d_in, const int* in_sizes, int n_in,
                              void* d_out, int out_size, void* d_ws, size_t ws_size,
                              hipStream_t stream) {
    const float* qos  = (const float*)d_in[0];
    const float* uavg = (const float*)d_in[1];
    const float* usim = (const float*)d_in[2];
    const int*   uid  = (const int*)d_in[3];
    const int*   iid  = (const int*)d_in[4];
    const int*   tid  = (const int*)d_in[5];
    float* out = (float*)d_out;

    // ws layout: slotmap [T*I] ints | compact [B][U_PAD] floats
    const size_t smap_bytes = (size_t)T_DIM * I_DIM * sizeof(int);           // 1.152 MB
    const size_t off_compact = (smap_bytes + 255) & ~(size_t)255;
    const size_t need = off_compact + (size_t)B_DIM * U_PAD * sizeof(float); // ~10.6 MB

    if (ws_size >= need) {
        int*   slotmap = (int*)d_ws;
        float* compact = (float*)((char*)d_ws + off_compact);

        k_clear  <<<(T_DIM * I_DIM) / 256, 256, 0, stream>>>(slotmap);
        k_assign <<<B_DIM / 256,           256, 0, stream>>>(iid, tid, slotmap);
        // (i4-chunks, u-chunks of 16, t) = (5, 9, 64) = 2880 blocks x 4 waves
        dim3 eg((I4_DIM + 255) / 256, (U_DIM + 15) / 16, T_DIM);
        k_extract<<<eg,                    256, 0, stream>>>(qos, slotmap, compact);
        k_final  <<<B_DIM / 4,             256, 0, stream>>>(compact, uavg, usim,
                                                             uid, iid, tid, slotmap, out);
    } else {
        ucf_fallback<<<B_DIM / 4, 256, 0, stream>>>(qos, uavg, usim, uid, iid, tid, out);
    }
}

// Round 5
// 301.096 us; speedup vs baseline: 1.2234x; 1.1205x over previous
//
#include <hip/hip_runtime.h>
#include <math.h>

#define T_DIM 64
#define U_DIM 142
#define I_DIM 4500
#define I4_DIM 1125   // I_DIM/4
#define B_DIM 16384
#define K_TOP 10
#define U_PAD 144     // compact row stride (9 full 64B lines)

// ---------------- pass 1: slotmap = -1 (ws poisoned 0xAA each call) ---------
__global__ __launch_bounds__(256) void k_clear(int4* __restrict__ slotmap4) {
    const int idx = blockIdx.x * 256 + threadIdx.x;
    if (idx < (T_DIM * I_DIM) / 4)
        slotmap4[idx] = make_int4(-1, -1, -1, -1);
}

// ---------------- pass 2: owner slot per distinct (t,i) ---------------------
__global__ __launch_bounds__(256) void k_assign(const int* __restrict__ iid,
                                                const int* __restrict__ tid,
                                                int* __restrict__ slotmap) {
    const int b  = blockIdx.x * 256 + threadIdx.x;    // grid covers B exactly
    const int ti = tid[b] * I_DIM + iid[b];
    atomicCAS(&slotmap[ti], -1, b);   // first b wins; losers look it up later
}

// ---------------- pass 3: sparse extract, deep-MLP version ------------------
// Block = (i4-chunk of 256, u-chunk of 16, t). Thread owns one i4 (4 items).
// Retires iff ALL four slots empty (AND of sign bits). Survivors (~20%) issue
// ALL 16 u-row float4 loads back-to-back (no dependent work between them ->
// 16 outstanding loads/thread; R2/R4 had only 4 -> latency-bound at ~0.8-2
// TB/s). Loads are coalesced across the wave within each u-row (adjacent i4),
// so HBM sees quasi-sequential hit-line traffic.
// Write-line ownership: compact line (slot, u0..u0+15) = 64B written only by
// this block (U_PAD%16==0) -> no cross-XCD partial-line sharing.
__global__ __launch_bounds__(256) void k_extract(const float* __restrict__ qos,
                                                 const int* __restrict__ slotmap,
                                                 float* __restrict__ compact) {
    const int i4 = blockIdx.x * 256 + threadIdx.x;
    if (i4 >= I4_DIM) return;
    const int t  = blockIdx.z;
    const int u0 = blockIdx.y * 16;
    const int un = (u0 + 16 <= U_DIM) ? 16 : (U_DIM - u0);   // block-uniform

    const int4 ov = ((const int4*)(slotmap + (size_t)t * I_DIM))[i4];
    if ((ov.x & ov.y & ov.z & ov.w) < 0) return;   // ALL -1: nothing needed

    const float4* qcol4 = (const float4*)qos + ((size_t)t * U_DIM + u0) * I4_DIM + i4;

    float4 q[16];
#pragma unroll
    for (int j = 0; j < 16; ++j)
        if (j < un) q[j] = qcol4[(size_t)j * I4_DIM];   // 16 loads in flight

#pragma unroll
    for (int j = 0; j < 16; ++j) {
        if (j < un) {
            const int u = u0 + j;
            if (ov.x >= 0) compact[(size_t)ov.x * U_PAD + u] = q[j].x;
            if (ov.y >= 0) compact[(size_t)ov.y * U_PAD + u] = q[j].y;
            if (ov.z >= 0) compact[(size_t)ov.z * U_PAD + u] = q[j].z;
            if (ov.w >= 0) compact[(size_t)ov.w * U_PAD + u] = q[j].w;
        }
    }
}

// ---------------- pass 4: wave-per-b top-k (proven, absmax 0) ---------------
__global__ __launch_bounds__(256) void k_final(
    const float* __restrict__ compact,
    const float* __restrict__ user_avg,  // [T,U]
    const float* __restrict__ user_sim,  // [U,U]
    const int*   __restrict__ uid,
    const int*   __restrict__ iid,
    const int*   __restrict__ tid,
    const int*   __restrict__ slotmap,
    float*       __restrict__ out)
{
    const int lane = threadIdx.x & 63;
    const int wid  = threadIdx.x >> 6;
    const int b    = blockIdx.x * 4 + wid;      // grid covers B exactly

    const int u = uid[b];
    const int i = iid[b];
    const int t = tid[b];
    const int o = slotmap[t * I_DIM + i];       // >= 0 after assign

    const float* crow = compact + (size_t)o * U_PAD;   // contiguous 568 B
    const float* srow = user_sim + (size_t)u * U_DIM;
    const float* arow = user_avg + (size_t)t * U_DIM;

    float val[3], con[3];
#pragma unroll
    for (int j = 0; j < 3; ++j) {
        const int v = lane + j * 64;
        float sv = -INFINITY, cv = 0.0f;
        if (v < U_DIM) {
            const float rv = crow[v];
            const float av = arow[v];
            const float s  = srow[v];
            sv = (rv > 0.0f) ? s : 0.0f;
            cv = sv * (rv - av);
        }
        val[j] = sv; con[j] = cv;
    }

    float ssum = 0.0f, wsum = 0.0f;
#pragma unroll
    for (int k = 0; k < K_TOP; ++k) {
        float mv = val[0]; float mc = con[0]; int mk = lane;
        if (val[1] > mv) { mv = val[1]; mc = con[1]; mk = lane + 64; }
        if (val[2] > mv) { mv = val[2]; mc = con[2]; mk = lane + 128; }
#pragma unroll
        for (int off = 32; off > 0; off >>= 1) {
            const float ov = __shfl_xor(mv, off, 64);
            const float oc = __shfl_xor(mc, off, 64);
            const int   ok = __shfl_xor(mk, off, 64);
            if (ov > mv || (ov == mv && ok < mk)) { mv = ov; mc = oc; mk = ok; }
        }
        ssum += mv; wsum += mc;
        if ((mk & 63) == lane) {
            const int slot = mk >> 6;
            if (slot == 0)      val[0] = -INFINITY;
            else if (slot == 1) val[1] = -INFINITY;
            else                val[2] = -INFINITY;
        }
    }

    if (lane == 0) out[b] = arow[u] + wsum / (ssum + 1e-8f);
}

// ---------------- fallback (round-0 random-gather kernel) -------------------
__global__ __launch_bounds__(256) void ucf_fallback(
    const float* __restrict__ qos, const float* __restrict__ user_avg,
    const float* __restrict__ user_sim, const int* __restrict__ uid,
    const int* __restrict__ iid, const int* __restrict__ tid,
    float* __restrict__ out)
{
    const int lane = threadIdx.x & 63;
    const int wid  = threadIdx.x >> 6;
    const int b    = blockIdx.x * 4 + wid;
    const int u = uid[b], i = iid[b], t = tid[b];
    const float* qcol = qos + ((size_t)t * U_DIM) * (size_t)I_DIM + i;
    const float* srow = user_sim + (size_t)u * U_DIM;
    const float* arow = user_avg + (size_t)t * U_DIM;
    float val[3], con[3];
#pragma unroll
    for (int j = 0; j < 3; ++j) {
        const int v = lane + j * 64;
        float sv = -INFINITY, cv = 0.0f;
        if (v < U_DIM) {
            const float rv = qcol[(size_t)v * I_DIM];
            sv = (rv > 0.0f) ? srow[v] : 0.0f;
            cv = sv * (rv - arow[v]);
        }
        val[j] = sv; con[j] = cv;
    }
    float ssum = 0.0f, wsum = 0.0f;
#pragma unroll
    for (int k = 0; k < K_TOP; ++k) {
        float mv = val[0]; float mc = con[0]; int mk = lane;
        if (val[1] > mv) { mv = val[1]; mc = con[1]; mk = lane + 64; }
        if (val[2] > mv) { mv = val[2]; mc = con[2]; mk = lane + 128; }
#pragma unroll
        for (int off = 32; off > 0; off >>= 1) {
            const float ov = __shfl_xor(mv, off, 64);
            const float oc = __shfl_xor(mc, off, 64);
            const int   ok = __shfl_xor(mk, off, 64);
            if (ov > mv || (ov == mv && ok < mk)) { mv = ov; mc = oc; mk = ok; }
        }
        ssum += mv; wsum += mc;
        if ((mk & 63) == lane) {
            const int slot = mk >> 6;
            if (slot == 0)      val[0] = -INFINITY;
            else if (slot == 1) val[1] = -INFINITY;
            else                val[2] = -INFINITY;
        }
    }
    if (lane == 0) out[b] = arow[u] + wsum / (ssum + 1e-8f);
}

extern "C" void kernel_launch(void* const* d_in, const int* in_sizes, int n_in,
                              void* d_out, int out_size, void* d_ws, size_t ws_size,
                              hipStream_t stream) {
    const float* qos  = (const float*)d_in[0];
    const float* uavg = (const float*)d_in[1];
    const float* usim = (const float*)d_in[2];
    const int*   uid  = (const int*)d_in[3];
    const int*   iid  = (const int*)d_in[4];
    const int*   tid  = (const int*)d_in[5];
    float* out = (float*)d_out;

    // ws layout: slotmap [T*I] ints | compact [B][U_PAD] floats
    const size_t smap_bytes = (size_t)T_DIM * I_DIM * sizeof(int);           // 1.152 MB
    const size_t off_compact = (smap_bytes + 255) & ~(size_t)255;
    const size_t need = off_compact + (size_t)B_DIM * U_PAD * sizeof(float); // ~10.6 MB

    if (ws_size >= need) {
        int*   slotmap = (int*)d_ws;
        float* compact = (float*)((char*)d_ws + off_compact);

        k_clear  <<<(T_DIM * I_DIM / 4 + 255) / 256, 256, 0, stream>>>((int4*)slotmap);
        k_assign <<<B_DIM / 256,                     256, 0, stream>>>(iid, tid, slotmap);
        // (i4-chunks, u-chunks of 16, t) = (5, 9, 64) = 2880 blocks x 4 waves
        dim3 eg((I4_DIM + 255) / 256, (U_DIM + 15) / 16, T_DIM);
        k_extract<<<eg,                              256, 0, stream>>>(qos, slotmap, compact);
        k_final  <<<B_DIM / 4,                       256, 0, stream>>>(compact, uavg, usim,
                                                                       uid, iid, tid, slotmap, out);
    } else {
        ucf_fallback<<<B_DIM / 4, 256, 0, stream>>>(qos, uavg, usim, uid, iid, tid, out);
    }
}

// Round 6
// 288.158 us; speedup vs baseline: 1.2783x; 1.0449x over previous
//
#include <hip/hip_runtime.h>
#include <math.h>

#define T_DIM 64
#define U_DIM 142
#define I_DIM 4500
#define I4_DIM 1125   // I_DIM/4
#define B_DIM 16384
#define K_TOP 10
#define U_PAD 144     // compact row stride (9 full 64B lines, 36 float4)
#define CHUNK_I4 128  // 512 items per extract block
#define CAP 72        // LDS-buffered needed cols per chunk (lambda=28.3, +8sigma)

// ---------------- pass 1: slotmap = -1 (ws poisoned 0xAA each call) ---------
__global__ __launch_bounds__(256) void k_clear(int4* __restrict__ slotmap4) {
    const int idx = blockIdx.x * 256 + threadIdx.x;
    if (idx < (T_DIM * I_DIM) / 4)
        slotmap4[idx] = make_int4(-1, -1, -1, -1);
}

// ---------------- pass 2: owner slot per distinct (t,i) ---------------------
__global__ __launch_bounds__(256) void k_assign(const int* __restrict__ iid,
                                                const int* __restrict__ tid,
                                                int* __restrict__ slotmap) {
    const int b  = blockIdx.x * 256 + threadIdx.x;    // grid covers B exactly
    const int ti = tid[b] * I_DIM + iid[b];
    atomicCAS(&slotmap[ti], -1, b);   // first b wins; losers read owner's row
}

// ---------------- pass 3: compacted-gather extract --------------------------
// Block = (i4-chunk of 128, t). Phase A compacts the hit-i4 list and the
// needed-column list into LDS (fully-active work afterwards — R5's flaw was
// ~13/64 scattered active lanes per gather). Phase B: lane h gathers hit-i4 h
// across 4 unrolled u-rows (4 x ~26 useful lines in flight per wave; every
// fetched line contains needed data -> ~98 MB total, ascending order).
// Scatter lands in an LDS tile [col][U_PAD]; phase C writes compact rows
// fully coalesced as float4. Overflow beyond CAP (never in practice) takes a
// direct-global-store path for correctness.
__global__ __launch_bounds__(256) void k_extract(const float* __restrict__ qos,
                                                 const int* __restrict__ slotmap,
                                                 float* __restrict__ compact) {
    __shared__ int  s_nhit, s_ncol;
    __shared__ int  s_hit_i4[CHUNK_I4];
    __shared__ int4 s_hit_cols[CHUNK_I4];
    __shared__ int4 s_hit_own[CHUNK_I4];
    __shared__ int  s_col_b[CAP];
    __shared__ __align__(16) float s_tile[CAP * U_PAD];   // 41.5 KB

    const int t   = blockIdx.y;
    const int c0  = blockIdx.x * CHUNK_I4;
    const int ni4 = (c0 + CHUNK_I4 <= I4_DIM) ? CHUNK_I4 : (I4_DIM - c0);
    const int tid = threadIdx.x;

    if (tid == 0) { s_nhit = 0; s_ncol = 0; }
    __syncthreads();

    // ---- phase A: compact hit list ----
    if (tid < ni4) {
        const int4 ov = ((const int4*)(slotmap + (size_t)t * I_DIM))[c0 + tid];
        if ((ov.x & ov.y & ov.z & ov.w) >= 0) {       // any slot >= 0
            const int h = atomicAdd(&s_nhit, 1);
            s_hit_i4[h]  = c0 + tid;
            s_hit_own[h] = ov;
            int4 cols;
            cols.x = (ov.x >= 0) ? atomicAdd(&s_ncol, 1) : -1;
            cols.y = (ov.y >= 0) ? atomicAdd(&s_ncol, 1) : -1;
            cols.z = (ov.z >= 0) ? atomicAdd(&s_ncol, 1) : -1;
            cols.w = (ov.w >= 0) ? atomicAdd(&s_ncol, 1) : -1;
            s_hit_cols[h] = cols;
            if (cols.x >= 0 && cols.x < CAP) s_col_b[cols.x] = ov.x;
            if (cols.y >= 0 && cols.y < CAP) s_col_b[cols.y] = ov.y;
            if (cols.z >= 0 && cols.z < CAP) s_col_b[cols.z] = ov.z;
            if (cols.w >= 0 && cols.w < CAP) s_col_b[cols.w] = ov.w;
        }
    }
    __syncthreads();

    const int nhit = s_nhit;
    const int ncol = (s_ncol < CAP) ? s_ncol : CAP;

    // ---- phase B: fully-active gather, 4 u-rows in flight ----
    const int lane = tid & 63;
    const int w    = tid >> 6;
    const int ustart = w * 36;
    const int uend   = (ustart + 36 < U_DIM) ? (ustart + 36) : U_DIM;

    for (int hb = 0; hb < nhit; hb += 64) {           // 1 iteration in practice
        const int  h   = hb + lane;
        const bool act = (h < nhit);
        const int  i4g = act ? s_hit_i4[h] : 0;
        int4 cols = make_int4(-1, -1, -1, -1);
        int4 own  = make_int4(0, 0, 0, 0);
        if (act) { cols = s_hit_cols[h]; own = s_hit_own[h]; }
        const float4* qb = (const float4*)qos + (size_t)t * U_DIM * I4_DIM + i4g;

        for (int u0 = ustart; u0 < uend; u0 += 4) {
            const int m = (uend - u0 < 4) ? (uend - u0) : 4;
            float4 q[4];
#pragma unroll
            for (int j = 0; j < 4; ++j)
                if (act && j < m) q[j] = qb[(size_t)(u0 + j) * I4_DIM];
#pragma unroll
            for (int j = 0; j < 4; ++j) {
                if (act && j < m) {
                    const int u = u0 + j;
#define SCATTER(QV, CC, OO)                                                   \
    if ((CC) >= 0) {                                                          \
        if ((CC) < CAP) s_tile[(CC) * U_PAD + u] = (QV);                      \
        else compact[(size_t)(OO) * U_PAD + u] = (QV);                        \
    }
                    SCATTER(q[j].x, cols.x, own.x)
                    SCATTER(q[j].y, cols.y, own.y)
                    SCATTER(q[j].z, cols.z, own.z)
                    SCATTER(q[j].w, cols.w, own.w)
#undef SCATTER
                }
            }
        }
    }
    __syncthreads();

    // ---- phase C: coalesced compact writes (36 float4 per col) ----
    float4* cmp4 = (float4*)compact;
    const float4* tile4 = (const float4*)s_tile;
    const int nf = ncol * 36;
    for (int idx = tid; idx < nf; idx += 256) {
        const int c = idx / 36;
        const int f = idx - c * 36;
        cmp4[(size_t)s_col_b[c] * 36 + f] = tile4[c * 36 + f];
    }
}

// ---------------- pass 4: wave-per-b top-k (proven, absmax 0) ---------------
__global__ __launch_bounds__(256) void k_final(
    const float* __restrict__ compact,
    const float* __restrict__ user_avg,  // [T,U]
    const float* __restrict__ user_sim,  // [U,U]
    const int*   __restrict__ uid,
    const int*   __restrict__ iid,
    const int*   __restrict__ tid,
    const int*   __restrict__ slotmap,
    float*       __restrict__ out)
{
    const int lane = threadIdx.x & 63;
    const int wid  = threadIdx.x >> 6;
    const int b    = blockIdx.x * 4 + wid;      // grid covers B exactly

    const int u = uid[b];
    const int i = iid[b];
    const int t = tid[b];
    const int o = slotmap[t * I_DIM + i];       // >= 0 after assign

    const float* crow = compact + (size_t)o * U_PAD;   // contiguous 568 B
    const float* srow = user_sim + (size_t)u * U_DIM;
    const float* arow = user_avg + (size_t)t * U_DIM;

    float val[3], con[3];
#pragma unroll
    for (int j = 0; j < 3; ++j) {
        const int v = lane + j * 64;
        float sv = -INFINITY, cv = 0.0f;
        if (v < U_DIM) {
            const float rv = crow[v];
            const float av = arow[v];
            const float s  = srow[v];
            sv = (rv > 0.0f) ? s : 0.0f;
            cv = sv * (rv - av);
        }
        val[j] = sv; con[j] = cv;
    }

    float ssum = 0.0f, wsum = 0.0f;
#pragma unroll
    for (int k = 0; k < K_TOP; ++k) {
        float mv = val[0]; float mc = con[0]; int mk = lane;
        if (val[1] > mv) { mv = val[1]; mc = con[1]; mk = lane + 64; }
        if (val[2] > mv) { mv = val[2]; mc = con[2]; mk = lane + 128; }
#pragma unroll
        for (int off = 32; off > 0; off >>= 1) {
            const float ov = __shfl_xor(mv, off, 64);
            const float oc = __shfl_xor(mc, off, 64);
            const int   ok = __shfl_xor(mk, off, 64);
            if (ov > mv || (ov == mv && ok < mk)) { mv = ov; mc = oc; mk = ok; }
        }
        ssum += mv; wsum += mc;
        if ((mk & 63) == lane) {
            const int slot = mk >> 6;
            if (slot == 0)      val[0] = -INFINITY;
            else if (slot == 1) val[1] = -INFINITY;
            else                val[2] = -INFINITY;
        }
    }

    if (lane == 0) out[b] = arow[u] + wsum / (ssum + 1e-8f);
}

// ---------------- fallback (round-0 random-gather kernel) -------------------
__global__ __launch_bounds__(256) void ucf_fallback(
    const float* __restrict__ qos, const float* __restrict__ user_avg,
    const float* __restrict__ user_sim, const int* __restrict__ uid,
    const int* __restrict__ iid, const int* __restrict__ tid,
    float* __restrict__ out)
{
    const int lane = threadIdx.x & 63;
    const int wid  = threadIdx.x >> 6;
    const int b    = blockIdx.x * 4 + wid;
    const int u = uid[b], i = iid[b], t = tid[b];
    const float* qcol = qos + ((size_t)t * U_DIM) * (size_t)I_DIM + i;
    const float* srow = user_sim + (size_t)u * U_DIM;
    const float* arow = user_avg + (size_t)t * U_DIM;
    float val[3], con[3];
#pragma unroll
    for (int j = 0; j < 3; ++j) {
        const int v = lane + j * 64;
        float sv = -INFINITY, cv = 0.0f;
        if (v < U_DIM) {
            const float rv = qcol[(size_t)v * I_DIM];
            sv = (rv > 0.0f) ? srow[v] : 0.0f;
            cv = sv * (rv - arow[v]);
        }
        val[j] = sv; con[j] = cv;
    }
    float ssum = 0.0f, wsum = 0.0f;
#pragma unroll
    for (int k = 0; k < K_TOP; ++k) {
        float mv = val[0]; float mc = con[0]; int mk = lane;
        if (val[1] > mv) { mv = val[1]; mc = con[1]; mk = lane + 64; }
        if (val[2] > mv) { mv = val[2]; mc = con[2]; mk = lane + 128; }
#pragma unroll
        for (int off = 32; off > 0; off >>= 1) {
            const float ov = __shfl_xor(mv, off, 64);
            const float oc = __shfl_xor(mc, off, 64);
            const int   ok = __shfl_xor(mk, off, 64);
            if (ov > mv || (ov == mv && ok < mk)) { mv = ov; mc = oc; mk = ok; }
        }
        ssum += mv; wsum += mc;
        if ((mk & 63) == lane) {
            const int slot = mk >> 6;
            if (slot == 0)      val[0] = -INFINITY;
            else if (slot == 1) val[1] = -INFINITY;
            else                val[2] = -INFINITY;
        }
    }
    if (lane == 0) out[b] = arow[u] + wsum / (ssum + 1e-8f);
}

extern "C" void kernel_launch(void* const* d_in, const int* in_sizes, int n_in,
                              void* d_out, int out_size, void* d_ws, size_t ws_size,
                              hipStream_t stream) {
    const float* qos  = (const float*)d_in[0];
    const float* uavg = (const float*)d_in[1];
    const float* usim = (const float*)d_in[2];
    const int*   uid  = (const int*)d_in[3];
    const int*   iid  = (const int*)d_in[4];
    const int*   tid  = (const int*)d_in[5];
    float* out = (float*)d_out;

    // ws layout: slotmap [T*I] ints | compact [B][U_PAD] floats
    const size_t smap_bytes = (size_t)T_DIM * I_DIM * sizeof(int);           // 1.152 MB
    const size_t off_compact = (smap_bytes + 255) & ~(size_t)255;
    const size_t need = off_compact + (size_t)B_DIM * U_PAD * sizeof(float); // ~10.6 MB

    if (ws_size >= need) {
        int*   slotmap = (int*)d_ws;
        float* compact = (float*)((char*)d_ws + off_compact);

        k_clear  <<<(T_DIM * I_DIM / 4 + 255) / 256, 256, 0, stream>>>((int4*)slotmap);
        k_assign <<<B_DIM / 256,                     256, 0, stream>>>(iid, tid, slotmap);
        dim3 eg((I4_DIM + CHUNK_I4 - 1) / CHUNK_I4, T_DIM);   // (9, 64) = 576 blocks
        k_extract<<<eg,                              256, 0, stream>>>(qos, slotmap, compact);
        k_final  <<<B_DIM / 4,                       256, 0, stream>>>(compact, uavg, usim,
                                                                       uid, iid, tid, slotmap, out);
    } else {
        ucf_fallback<<<B_DIM / 4, 256, 0, stream>>>(qos, uavg, usim, uid, iid, tid, out);
    }
}